// Round 3
// baseline (83201.453 us; speedup 1.0000x reference)
//
#include <hip/hip_runtime.h>
#include <hip/hip_bf16.h>
#include <hip/hip_fp16.h>

#define N_EV   4096
#define NDIMS_ 128
#define H_     1024
#define E_     512
#define MC_    64
#define SIXH   6144
#define NB_    128     // persistent scan blocks (<= 256 CUs -> co-resident by capacity)
#define UPB    8       // hidden units per scan block
#define NROWS  48      // 6 gates * UPB rows of Wh per block
#define NSNAP  (N_EV + 1)
#define APITCH 513     // uints per m-row of A in k_mc LDS (odd -> conflict-free)

// ---------------- fast math helpers ----------------
__device__ __forceinline__ float frcp(float x){ return __builtin_amdgcn_rcpf(x); }
__device__ __forceinline__ float fsigmoid(float x){ return frcp(1.f + __expf(-x)); }
__device__ __forceinline__ float ftanh(float x){
  float t = __expf(-2.f * fabsf(x));
  float r = (1.f - t) * frcp(1.f + t);
  return copysignf(r, x);
}
__device__ __forceinline__ float fsoftplus(float x){
  if (x > 15.f) return x;
  float e = __expf(x);
  if (x < -15.f) return e;
  return __logf(1.f + e);
}
__device__ __forceinline__ unsigned short f2bf(float f){
  unsigned int u = __float_as_uint(f);
  unsigned int r = u + 0x7fffu + ((u >> 16) & 1u);
  return (unsigned short)(r >> 16);
}
__device__ __forceinline__ float bflo(unsigned int p){ return __uint_as_float(p << 16); }
__device__ __forceinline__ float bfhi(unsigned int p){ return __uint_as_float(p & 0xffff0000u); }
__device__ __forceinline__ float activate(int g, float x){
  // gates order: 0 i(sig), 1 f(sig), 2 o(sig), 3 z(tanh), 4 cbar(tanh), 5 delta(softplus)
  if (g < 3) return fsigmoid(x);
  if (g < 5) return ftanh(x);
  return fsoftplus(x);
}
__device__ __forceinline__ float waveRed(float v){
  for (int o = 32; o; o >>= 1) v += __shfl_down(v, o);
  return v;
}
__device__ __forceinline__ float decode_T(const int* p){
  int iv = *p;                       // robust: int 110 or float 110.0f bit pattern
  if (iv < 0 || iv > 16777216) return __int_as_float(iv);
  return (float)iv;
}

// ---------------- init: zero flags + ll ----------------
__global__ void k_init(int* flags, float* misc){
  int i = blockIdx.x * blockDim.x + threadIdx.x;
  if (i < NB_ * 32) flags[i] = 0;
  if (i == 0) misc[0] = 0.f;
}

// ---------------- Gx[type][row] = W_gates[row, :E] . emb[type] + b_gates[row] ----------------
__global__ void k_gx(const float* __restrict__ Wg, const float* __restrict__ bg,
                     const float* __restrict__ emb, float* __restrict__ Gx){
  int wave = threadIdx.x >> 6, lane = threadIdx.x & 63;
  int row = blockIdx.x * 4 + wave;               // grid 1536 -> 6144 rows
  const float4 wa = *(const float4*)(Wg + (size_t)row * 1536 + 4 * lane);
  const float4 wb = *(const float4*)(Wg + (size_t)row * 1536 + 256 + 4 * lane);
  float bias = bg[row];
  for (int ty = 0; ty <= NDIMS_; ++ty){
    const float4 ea = *(const float4*)(emb + ty * E_ + 4 * lane);
    const float4 eb = *(const float4*)(emb + ty * E_ + 256 + 4 * lane);
    float acc = wa.x*ea.x + wa.y*ea.y + wa.z*ea.z + wa.w*ea.w
              + wb.x*eb.x + wb.y*eb.y + wb.z*eb.z + wb.w*eb.w;
    acc = waveRed(acc);
    if (lane == 0) Gx[ty * SIXH + row] = acc + bias;
  }
}

// ---------------- pack Wh (h-columns of W_gates) to bf16, per-block layout ----------------
__global__ void k_pack(const float* __restrict__ Wg, unsigned int* __restrict__ Whb){
  int p = blockIdx.x * blockDim.x + threadIdx.x;   // pair index over 128*48*512
  if (p >= NB_ * NROWS * 512) return;
  int b  = p / (NROWS * 512);
  int r2 = p - b * (NROWS * 512);
  int rl = r2 >> 9, kp = r2 & 511;
  int g = rl >> 3, uu = rl & 7;
  int srow = g * H_ + b * UPB + uu;
  const float* src = Wg + (size_t)srow * 1536 + E_ + 2 * kp;
  unsigned int lo = f2bf(src[0]);
  unsigned int hi = f2bf(src[1]);
  Whb[p] = lo | (hi << 16);                        // Whb[b][rl][kp]
}

// ---------------- sequential scan (128 persistent blocks x 1024 thr) ----------------
__global__ void __launch_bounds__(1024)
k_scan(const float* __restrict__ times, const int* __restrict__ dims,
       const float* __restrict__ Gx, const unsigned int* __restrict__ Whb,
       const float* __restrict__ Wint, const float* __restrict__ bint,
       __half* __restrict__ Sc, __half* __restrict__ Scb,
       __half* __restrict__ Sd, __half* __restrict__ So,
       float* hbuf, int* flags, float* misc)
{
  extern __shared__ char smem[];
  unsigned int* Wl   = (unsigned int*)smem;                 // 48*512 uints = 98304 B
  float* h_lds       = (float*)(smem + 98304);              // 4096 B
  float* g_lds       = (float*)(smem + 98304 + 4096);       // 48
  float* act_lds     = g_lds + NROWS;                       // 48
  float* red         = act_lds + NROWS;                     // 16

  const int tid = threadIdx.x, blk = blockIdx.x;
  const int wave = tid >> 6, lane = tid & 63;

  // stage this block's Wh slice into LDS
  const unsigned int* wsrc = Whb + (size_t)blk * (NROWS * 512);
  for (int i = tid; i < NROWS * 512; i += 1024) Wl[i] = wsrc[i];

  // ---- BOS update: h0=c0=0 so g = Gx[NDIMS] ----
  if (tid < NROWS){
    float pre = Gx[NDIMS_ * SIXH + (tid >> 3) * H_ + blk * UPB + (tid & 7)];
    act_lds[tid] = activate(tid >> 3, pre);
  }
  __syncthreads();

  float c = 0.f, cbar = 0.f, delta = 0.f, oo = 0.f;
  if (tid < UPB){
    float i_ = act_lds[tid],      f_ = act_lds[8 + tid],  og = act_lds[16 + tid];
    float z_ = act_lds[24 + tid], cb = act_lds[32 + tid], dl = act_lds[40 + tid];
    (void)f_;
    c = i_ * z_; cbar = cb; delta = dl; oo = og;
    int j = blk * UPB + tid;
    Sc[j] = __float2half(c);  Scb[j] = __float2half(cbar);
    Sd[j] = __float2half(delta); So[j] = __float2half(oo);
  }

  float llacc = 0.f;
  float prev_t = 0.f;

  for (int n = 0; n < N_EV; ++n){
    float t_n = times[n];
    int   d_n = dims[n];
    float dt = fmaxf(t_n - prev_t, 0.f); prev_t = t_n;

    // prefetch (used after the barrier; overlaps barrier latency)
    float gxv = (tid < NROWS) ? Gx[d_n * SIXH + (tid >> 3) * H_ + blk * UPB + (tid & 7)] : 0.f;
    float w_i = (blk == 0) ? Wint[d_n * H_ + tid] : 0.f;

    // decay local units to event time, publish h_t slice
    float c_t = 0.f;
    if (tid < UPB){
      float e = __expf(-delta * dt);
      c_t = cbar + (c - cbar) * e;
      float h_u = oo * ftanh(c_t);
      hbuf[((n & 1) << 10) + blk * UPB + tid] = h_u;
    }
    __syncthreads();                                   // drains stores (vmcnt) pre-barrier
    if (tid == 0){
      __builtin_amdgcn_fence(__ATOMIC_RELEASE, "agent");   // L2 writeback (XCD non-coherence)
      __hip_atomic_store(&flags[blk * 32], n + 1, __ATOMIC_RELAXED, __HIP_MEMORY_SCOPE_AGENT);
    }
    if (tid < NB_){
      while (__hip_atomic_load(&flags[tid * 32], __ATOMIC_RELAXED, __HIP_MEMORY_SCOPE_AGENT) < n + 1)
        __builtin_amdgcn_s_sleep(1);
    }
    __syncthreads();
    __builtin_amdgcn_fence(__ATOMIC_ACQUIRE, "agent"); // invalidate stale caches

    h_lds[tid] = hbuf[((n & 1) << 10) + tid];
    __syncthreads();

    // block 0: log-likelihood term, partial reduce
    if (blk == 0){
      float p = w_i * h_lds[tid];
      p = waveRed(p);
      if (lane == 0) red[wave] = p;
    }

    // matvec: 48 rows x 1024, 16 waves x 3 rows
    const float2* h2 = (const float2*)h_lds;
    for (int r3 = 0; r3 < 3; ++r3){
      int row = wave * 3 + r3;
      const unsigned int* wrow = Wl + row * 512;
      float acc = 0.f;
      #pragma unroll
      for (int i2 = 0; i2 < 8; ++i2){
        unsigned int wp = wrow[lane + (i2 << 6)];
        float2 hv = h2[lane + (i2 << 6)];
        acc = fmaf(bflo(wp), hv.x, acc);
        acc = fmaf(bfhi(wp), hv.y, acc);
      }
      acc = waveRed(acc);
      if (lane == 0) g_lds[row] = acc;
    }
    __syncthreads();

    if (tid < NROWS) act_lds[tid] = activate(tid >> 3, g_lds[tid] + gxv);
    if (blk == 0 && tid == 0){
      float v = bint[d_n];
      #pragma unroll
      for (int w = 0; w < 16; ++w) v += red[w];
      llacc += __logf(fmaxf(fsoftplus(v), 1e-8f));
    }
    __syncthreads();

    if (tid < UPB){
      float i_ = act_lds[tid],      f_ = act_lds[8 + tid],  og = act_lds[16 + tid];
      float z_ = act_lds[24 + tid], cb = act_lds[32 + tid], dl = act_lds[40 + tid];
      c = f_ * c_t + i_ * z_; cbar = cb; delta = dl; oo = og;
      int j = (n + 1) * H_ + blk * UPB + tid;
      Sc[j] = __float2half(c);  Scb[j] = __float2half(cbar);
      Sd[j] = __float2half(delta); So[j] = __float2half(oo);
    }
  }
  if (blk == 0 && tid == 0) misc[0] = llacc;
}

// ---------------- parallel MC integral per interval ----------------
__global__ void __launch_bounds__(1024)
k_mc(const float* __restrict__ times, const float* __restrict__ uin,
     const float* __restrict__ Wint, const float* __restrict__ bint,
     const __half* __restrict__ Sc, const __half* __restrict__ Scb,
     const __half* __restrict__ Sd, const __half* __restrict__ So,
     const int* __restrict__ tend_p, float* __restrict__ partial)
{
  extern __shared__ char smem[];
  unsigned int* A = (unsigned int*)smem;                 // 64 * 513 * 4 = 131328 B
  float* scb = (float*)(smem + 64 * APITCH * 4);         // 4 * 4096 B state
  float* sa  = scb + H_;
  float* sdl = sa + H_;
  float* so  = sdl + H_;
  float* red = so + H_;                                  // 16*64 floats

  const int k = blockIdx.x, tid = threadIdx.x;
  const int wave = tid >> 6, lane = tid & 63;

  // stage interval state
  {
    float cv = __half2float(Sc[(size_t)k * H_ + tid]);
    float cb = __half2float(Scb[(size_t)k * H_ + tid]);
    scb[tid] = cb; sa[tid] = cv - cb;
    sdl[tid] = __half2float(Sd[(size_t)k * H_ + tid]);
    so[tid]  = __half2float(So[(size_t)k * H_ + tid]);
  }
  float T_end = decode_T(tend_p);
  float dt;
  if (k == 0)           dt = times[0];
  else if (k < N_EV)    dt = times[k] - times[k - 1];
  else                  dt = T_end - times[N_EV - 1];
  dt = fmaxf(dt, 0.f);
  __syncthreads();

  // a_s = o * tanh(cbar + (c - cbar) * exp(-u*dt*delta)); A[m][j] bf16
  const int m = lane, s = wave;                  // wave-uniform j stripe -> broadcast LDS reads
  float sdt = uin[(size_t)k * MC_ + m] * dt;
  unsigned int* Arow = A + m * APITCH;
  for (int i = 0; i < 64; i += 2){
    int j = (s << 6) + i;
    float d0 = __expf(-sdt * sdl[j]);
    float d1 = __expf(-sdt * sdl[j + 1]);
    float a0 = so[j]     * ftanh(scb[j]     + sa[j]     * d0);
    float a1 = so[j + 1] * ftanh(scb[j + 1] + sa[j + 1] * d1);
    Arow[j >> 1] = (unsigned int)f2bf(a0) | ((unsigned int)f2bf(a1) << 16);
  }
  __syncthreads();

  // lam sums: wave handles 8 dims, lane = m; W loads scalarized
  int d0i = __builtin_amdgcn_readfirstlane(wave * 8);
  const float* wbase = Wint + (size_t)d0i * H_;
  float acc[8];
  #pragma unroll
  for (int dd = 0; dd < 8; ++dd) acc[dd] = 0.f;
  for (int kk = 0; kk < 512; ++kk){
    unsigned int ap = Arow[kk];
    float a0 = bflo(ap), a1 = bfhi(ap);
    #pragma unroll
    for (int dd = 0; dd < 8; ++dd){
      const float2 wv = *(const float2*)(wbase + (size_t)dd * H_ + 2 * kk);
      acc[dd] = fmaf(a0, wv.x, acc[dd]);
      acc[dd] = fmaf(a1, wv.y, acc[dd]);
    }
  }
  float lamsum = 0.f;
  #pragma unroll
  for (int dd = 0; dd < 8; ++dd) lamsum += fsoftplus(acc[dd] + bint[d0i + dd]);
  red[wave * 64 + m] = lamsum;
  __syncthreads();

  if (tid < 64){
    float tot = 0.f;
    #pragma unroll
    for (int w = 0; w < 16; ++w) tot += red[w * 64 + tid];
    tot = waveRed(tot);
    if (tid == 0) partial[k] = dt * tot * (1.f / 64.f);
  }
}

// ---------------- final reduce ----------------
__global__ void k_red(const float* __restrict__ partial, const float* __restrict__ misc,
                      float* __restrict__ out){
  __shared__ float red[16];
  int tid = threadIdx.x;
  float s = 0.f;
  for (int i = tid; i < NSNAP; i += 1024) s += partial[i];
  s = waveRed(s);
  if ((tid & 63) == 0) red[tid >> 6] = s;
  __syncthreads();
  if (tid == 0){
    float tot = 0.f;
    #pragma unroll
    for (int w = 0; w < 16; ++w) tot += red[w];
    out[0] = misc[0] - tot;
  }
}

// ---------------- host ----------------
extern "C" void kernel_launch(void* const* d_in, const int* in_sizes, int n_in,
                              void* d_out, int out_size, void* d_ws, size_t ws_size,
                              hipStream_t stream) {
  const float* times = (const float*)d_in[0];
  const int*   dims  = (const int*)d_in[1];
  const float* emb   = (const float*)d_in[2];
  const float* Wg    = (const float*)d_in[3];
  const float* bg    = (const float*)d_in[4];
  const float* Wint  = (const float*)d_in[5];
  const float* bint  = (const float*)d_in[6];
  const float* uin   = (const float*)d_in[7];
  const int*   tend  = (const int*)d_in[8];
  float* out = (float*)d_out;

  char* ws = (char*)d_ws;
  const size_t GX_OFF   = 0;                       // 129*6144*4 = 3,170,304
  const size_t WHB_OFF  = 3170304;                 // 12,582,912
  const size_t SC_OFF   = 15753216;                // 8,390,656 each (fp16)
  const size_t SCB_OFF  = 24143872;
  const size_t SD_OFF   = 32534528;
  const size_t SO_OFF   = 40925184;
  const size_t HBUF_OFF = 49315840;                // 8192
  const size_t FLAG_OFF = 49324032;                // 16384
  const size_t MISC_OFF = 49340416;                // 256
  const size_t PART_OFF = 49340672;                // 16388

  float*        Gx    = (float*)(ws + GX_OFF);
  unsigned int* Whb   = (unsigned int*)(ws + WHB_OFF);
  __half*       Sc    = (__half*)(ws + SC_OFF);
  __half*       Scb   = (__half*)(ws + SCB_OFF);
  __half*       Sd    = (__half*)(ws + SD_OFF);
  __half*       So    = (__half*)(ws + SO_OFF);
  float*        hbuf  = (float*)(ws + HBUF_OFF);
  int*          flags = (int*)(ws + FLAG_OFF);
  float*        misc  = (float*)(ws + MISC_OFF);
  float*        part  = (float*)(ws + PART_OFF);

  const int SCAN_LDS = 98304 + 4096 + 4 * (NROWS + NROWS + 16);      // 102,848
  const int MC_LDS   = 64 * APITCH * 4 + 4 * H_ * 4 + 16 * 64 * 4;   // 151,808

  // host-side attribute set: not a stream op, safe under graph capture
  hipFuncSetAttribute((const void*)k_scan, hipFuncAttributeMaxDynamicSharedMemorySize, SCAN_LDS);
  hipFuncSetAttribute((const void*)k_mc,   hipFuncAttributeMaxDynamicSharedMemorySize, MC_LDS);

  k_init<<<16, 256, 0, stream>>>(flags, misc);
  k_gx<<<1536, 256, 0, stream>>>(Wg, bg, emb, Gx);
  k_pack<<<(NB_ * NROWS * 512 + 255) / 256, 256, 0, stream>>>(Wg, Whb);

  // Plain launch (NOT cooperative: cooperative launch can invalidate graph capture).
  // Co-residency by capacity: 128 blocks, 1 block/CU (102.8 KB LDS), 256 CUs.
  k_scan<<<dim3(NB_), dim3(1024), SCAN_LDS, stream>>>(times, dims, Gx, Whb, Wint, bint,
                                                      Sc, Scb, Sd, So, hbuf, flags, misc);

  k_mc<<<NSNAP, 1024, MC_LDS, stream>>>(times, uin, Wint, bint, Sc, Scb, Sd, So, tend, part);
  k_red<<<1, 1024, 0, stream>>>(part, misc, out);
}

// Round 7
// 16067.035 us; speedup vs baseline: 5.1784x; 5.1784x over previous
//
#include <hip/hip_runtime.h>
#include <hip/hip_bf16.h>
#include <hip/hip_fp16.h>

#define N_EV   4096
#define NDIMS_ 128
#define H_     1024
#define E_     512
#define MC_    64
#define SIXH   6144
#define NB_    128     // persistent scan blocks (1 blk/CU by LDS; 128 <= 256 CUs -> co-resident)
#define UPB    8       // hidden units per scan block
#define NROWS  48      // 6 gates * UPB rows of Wh per block
#define NSNAP  (N_EV + 1)
#define APITCH 513     // uints per m-row of A in k_mc LDS (odd -> conflict-free)

// ---------------- fast math helpers ----------------
__device__ __forceinline__ float frcp(float x){ return __builtin_amdgcn_rcpf(x); }
__device__ __forceinline__ float fsigmoid(float x){ return frcp(1.f + __expf(-x)); }
__device__ __forceinline__ float ftanh(float x){
  float t = __expf(-2.f * fabsf(x));
  float r = (1.f - t) * frcp(1.f + t);
  return copysignf(r, x);
}
__device__ __forceinline__ float fsoftplus(float x){
  if (x > 15.f) return x;
  float e = __expf(x);
  if (x < -15.f) return e;
  return __logf(1.f + e);
}
__device__ __forceinline__ unsigned short f2bf(float f){
  unsigned int u = __float_as_uint(f);
  unsigned int r = u + 0x7fffu + ((u >> 16) & 1u);
  return (unsigned short)(r >> 16);
}
__device__ __forceinline__ float bflo(unsigned int p){ return __uint_as_float(p << 16); }
__device__ __forceinline__ float bfhi(unsigned int p){ return __uint_as_float(p & 0xffff0000u); }
__device__ __forceinline__ float activate(int g, float x){
  // gates order: 0 i(sig), 1 f(sig), 2 o(sig), 3 z(tanh), 4 cbar(tanh), 5 delta(softplus)
  if (g < 3) return fsigmoid(x);
  if (g < 5) return ftanh(x);
  return fsoftplus(x);
}
__device__ __forceinline__ float waveRed(float v){
  for (int o = 32; o; o >>= 1) v += __shfl_down(v, o);
  return v;
}
__device__ __forceinline__ float decode_T(const int* p){
  int iv = *p;                       // robust: int 110 or float 110.0f bit pattern
  if (iv < 0 || iv > 16777216) return __int_as_float(iv);
  return (float)iv;
}

// ---------------- Gx[type][row] = W_gates[row, :E] . emb[type] + b_gates[row] ----------------
__global__ void k_gx(const float* __restrict__ Wg, const float* __restrict__ bg,
                     const float* __restrict__ emb, float* __restrict__ Gx){
  int wave = threadIdx.x >> 6, lane = threadIdx.x & 63;
  int row = blockIdx.x * 4 + wave;               // grid 1536 -> 6144 rows
  const float4 wa = *(const float4*)(Wg + (size_t)row * 1536 + 4 * lane);
  const float4 wb = *(const float4*)(Wg + (size_t)row * 1536 + 256 + 4 * lane);
  float bias = bg[row];
  for (int ty = 0; ty <= NDIMS_; ++ty){
    const float4 ea = *(const float4*)(emb + ty * E_ + 4 * lane);
    const float4 eb = *(const float4*)(emb + ty * E_ + 256 + 4 * lane);
    float acc = wa.x*ea.x + wa.y*ea.y + wa.z*ea.z + wa.w*ea.w
              + wb.x*eb.x + wb.y*eb.y + wb.z*eb.z + wb.w*eb.w;
    acc = waveRed(acc);
    if (lane == 0) Gx[ty * SIXH + row] = acc + bias;
  }
}

// ---------------- pack Wh (h-columns of W_gates) to bf16, per-block layout ----------------
__global__ void k_pack(const float* __restrict__ Wg, unsigned int* __restrict__ Whb){
  int p = blockIdx.x * blockDim.x + threadIdx.x;   // pair index over 128*48*512
  if (p >= NB_ * NROWS * 512) return;
  int b  = p / (NROWS * 512);
  int r2 = p - b * (NROWS * 512);
  int rl = r2 >> 9, kp = r2 & 511;
  int g = rl >> 3, uu = rl & 7;
  int srow = g * H_ + b * UPB + uu;
  const float* src = Wg + (size_t)srow * 1536 + E_ + 2 * kp;
  unsigned int lo = f2bf(src[0]);
  unsigned int hi = f2bf(src[1]);
  Whb[p] = lo | (hi << 16);                        // Whb[b][rl][kp]
}

// ---------------- sequential scan (128 persistent blocks x 1024 thr) ----------------
// Cross-block h exchange: 64-bit relaxed agent-scope atomics, {tag=n+1 | f32 h}.
// NO agent fences anywhere in the loop (they lowered to full-L2 wb/inv = the
// round-3 bottleneck: 388 MB HBM re-fetch + ~20us/step).
__global__ void __launch_bounds__(1024)
k_scan(const float* __restrict__ times, const int* __restrict__ dims,
       const float* __restrict__ Gx, const unsigned int* __restrict__ Whb,
       const float* __restrict__ Wint, const float* __restrict__ bint,
       __half* __restrict__ Sc, __half* __restrict__ Scb,
       __half* __restrict__ Sd, __half* __restrict__ So,
       unsigned long long* hbuf, float* misc)
{
  extern __shared__ char smem[];
  unsigned int* Wl   = (unsigned int*)smem;                 // 48*512 uints = 98304 B
  float* h_lds       = (float*)(smem + 98304);              // 4096 B
  float* g_lds       = (float*)(smem + 98304 + 4096);       // 48
  float* act_lds     = g_lds + NROWS;                       // 48
  float* red         = act_lds + NROWS;                     // 16

  const int tid = threadIdx.x, blk = blockIdx.x;
  const int wave = tid >> 6, lane = tid & 63;

  // stage this block's Wh slice into LDS
  const unsigned int* wsrc = Whb + (size_t)blk * (NROWS * 512);
  for (int i = tid; i < NROWS * 512; i += 1024) Wl[i] = wsrc[i];

  // ---- BOS update: h0=c0=0 so g = Gx[NDIMS] ----
  if (tid < NROWS){
    float pre = Gx[NDIMS_ * SIXH + (tid >> 3) * H_ + blk * UPB + (tid & 7)];
    act_lds[tid] = activate(tid >> 3, pre);
  }
  __syncthreads();

  float c = 0.f, cbar = 0.f, delta = 0.f, oo = 0.f;
  if (tid < UPB){
    float i_ = act_lds[tid],      og = act_lds[16 + tid];
    float z_ = act_lds[24 + tid], cb = act_lds[32 + tid], dl = act_lds[40 + tid];
    c = i_ * z_; cbar = cb; delta = dl; oo = og;
    int j = blk * UPB + tid;
    Sc[j] = __float2half(c);  Scb[j] = __float2half(cbar);
    Sd[j] = __float2half(delta); So[j] = __float2half(oo);
  }

  float llacc = 0.f;
  float prev_t = 0.f;

  for (int n = 0; n < N_EV; ++n){
    float t_n = times[n];
    int   d_n = dims[n];
    float dt = fmaxf(t_n - prev_t, 0.f); prev_t = t_n;

    // prefetch (used after the sync; L2-resident now that no invalidates happen)
    float gxv = (tid < NROWS) ? Gx[d_n * SIXH + (tid >> 3) * H_ + blk * UPB + (tid & 7)] : 0.f;
    float w_i = (blk == 0) ? Wint[d_n * H_ + tid] : 0.f;

    // decay local units to event time, publish h slice as {tag|bits} atomics
    float c_t = 0.f;
    if (tid < UPB){
      float e = __expf(-delta * dt);
      c_t = cbar + (c - cbar) * e;
      float h_u = oo * ftanh(c_t);
      unsigned long long msg = ((unsigned long long)(unsigned)(n + 1) << 32)
                             | (unsigned long long)__float_as_uint(h_u);
      __hip_atomic_store(&hbuf[((n & 1) << 10) + blk * UPB + tid], msg,
                         __ATOMIC_RELAXED, __HIP_MEMORY_SCOPE_AGENT);
    }
    asm volatile("" ::: "memory");   // compiler-only: keep stores above the spin

    // spin: each thread waits for its own h word (tag==n+1), then stage to LDS
    {
      const unsigned long long* src = &hbuf[((n & 1) << 10) + tid];
      unsigned long long v = __hip_atomic_load(src, __ATOMIC_RELAXED, __HIP_MEMORY_SCOPE_AGENT);
      while ((unsigned)(v >> 32) != (unsigned)(n + 1)){
        __builtin_amdgcn_s_sleep(1);
        v = __hip_atomic_load(src, __ATOMIC_RELAXED, __HIP_MEMORY_SCOPE_AGENT);
      }
      h_lds[tid] = __uint_as_float((unsigned)v);
    }
    __syncthreads();

    // block 0: log-likelihood term, partial reduce
    if (blk == 0){
      float p = w_i * h_lds[tid];
      p = waveRed(p);
      if (lane == 0) red[wave] = p;
    }

    // matvec: 48 rows x 1024, 16 waves x 3 rows
    const float2* h2 = (const float2*)h_lds;
    for (int r3 = 0; r3 < 3; ++r3){
      int row = wave * 3 + r3;
      const unsigned int* wrow = Wl + row * 512;
      float acc = 0.f;
      #pragma unroll
      for (int i2 = 0; i2 < 8; ++i2){
        unsigned int wp = wrow[lane + (i2 << 6)];
        float2 hv = h2[lane + (i2 << 6)];
        acc = fmaf(bflo(wp), hv.x, acc);
        acc = fmaf(bfhi(wp), hv.y, acc);
      }
      acc = waveRed(acc);
      if (lane == 0) g_lds[row] = acc;
    }
    __syncthreads();

    if (tid < NROWS) act_lds[tid] = activate(tid >> 3, g_lds[tid] + gxv);
    if (blk == 0 && tid == 0){
      float v = bint[d_n];
      #pragma unroll
      for (int w = 0; w < 16; ++w) v += red[w];
      llacc += __logf(fmaxf(fsoftplus(v), 1e-8f));
    }
    __syncthreads();

    if (tid < UPB){
      float i_ = act_lds[tid],      f_ = act_lds[8 + tid],  og = act_lds[16 + tid];
      float z_ = act_lds[24 + tid], cb = act_lds[32 + tid], dl = act_lds[40 + tid];
      c = f_ * c_t + i_ * z_; cbar = cb; delta = dl; oo = og;
      int j = (n + 1) * H_ + blk * UPB + tid;
      Sc[j] = __float2half(c);  Scb[j] = __float2half(cbar);
      Sd[j] = __float2half(delta); So[j] = __float2half(oo);
    }
  }
  if (blk == 0 && tid == 0) misc[0] = llacc;
}

// ---------------- parallel MC integral per interval ----------------
__global__ void __launch_bounds__(1024)
k_mc(const float* __restrict__ times, const float* __restrict__ uin,
     const float* __restrict__ Wint, const float* __restrict__ bint,
     const __half* __restrict__ Sc, const __half* __restrict__ Scb,
     const __half* __restrict__ Sd, const __half* __restrict__ So,
     const int* __restrict__ tend_p, float* __restrict__ partial)
{
  extern __shared__ char smem[];
  unsigned int* A = (unsigned int*)smem;                 // 64 * 513 * 4 = 131328 B
  float* scb = (float*)(smem + 64 * APITCH * 4);         // 4 * 4096 B state
  float* sa  = scb + H_;
  float* sdl = sa + H_;
  float* so  = sdl + H_;
  float* red = so + H_;                                  // 16*64 floats

  const int k = blockIdx.x, tid = threadIdx.x;
  const int wave = tid >> 6, lane = tid & 63;

  // stage interval state
  {
    float cv = __half2float(Sc[(size_t)k * H_ + tid]);
    float cb = __half2float(Scb[(size_t)k * H_ + tid]);
    scb[tid] = cb; sa[tid] = cv - cb;
    sdl[tid] = __half2float(Sd[(size_t)k * H_ + tid]);
    so[tid]  = __half2float(So[(size_t)k * H_ + tid]);
  }
  float T_end = decode_T(tend_p);
  float dt;
  if (k == 0)           dt = times[0];
  else if (k < N_EV)    dt = times[k] - times[k - 1];
  else                  dt = T_end - times[N_EV - 1];
  dt = fmaxf(dt, 0.f);
  __syncthreads();

  // a_s = o * tanh(cbar + (c - cbar) * exp(-u*dt*delta)); A[m][j] bf16
  const int m = lane, s = wave;                  // wave-uniform j stripe -> broadcast LDS reads
  float sdt = uin[(size_t)k * MC_ + m] * dt;
  unsigned int* Arow = A + m * APITCH;
  for (int i = 0; i < 64; i += 2){
    int j = (s << 6) + i;
    float d0 = __expf(-sdt * sdl[j]);
    float d1 = __expf(-sdt * sdl[j + 1]);
    float a0 = so[j]     * ftanh(scb[j]     + sa[j]     * d0);
    float a1 = so[j + 1] * ftanh(scb[j + 1] + sa[j + 1] * d1);
    Arow[j >> 1] = (unsigned int)f2bf(a0) | ((unsigned int)f2bf(a1) << 16);
  }
  __syncthreads();

  // lam sums: wave handles 8 dims, lane = m; W loads scalarized
  int d0i = __builtin_amdgcn_readfirstlane(wave * 8);
  const float* wbase = Wint + (size_t)d0i * H_;
  float acc[8];
  #pragma unroll
  for (int dd = 0; dd < 8; ++dd) acc[dd] = 0.f;
  for (int kk = 0; kk < 512; ++kk){
    unsigned int ap = Arow[kk];
    float a0 = bflo(ap), a1 = bfhi(ap);
    #pragma unroll
    for (int dd = 0; dd < 8; ++dd){
      const float2 wv = *(const float2*)(wbase + (size_t)dd * H_ + 2 * kk);
      acc[dd] = fmaf(a0, wv.x, acc[dd]);
      acc[dd] = fmaf(a1, wv.y, acc[dd]);
    }
  }
  float lamsum = 0.f;
  #pragma unroll
  for (int dd = 0; dd < 8; ++dd) lamsum += fsoftplus(acc[dd] + bint[d0i + dd]);
  red[wave * 64 + m] = lamsum;
  __syncthreads();

  if (tid < 64){
    float tot = 0.f;
    #pragma unroll
    for (int w = 0; w < 16; ++w) tot += red[w * 64 + tid];
    tot = waveRed(tot);
    if (tid == 0) partial[k] = dt * tot * (1.f / 64.f);
  }
}

// ---------------- final reduce ----------------
__global__ void k_red(const float* __restrict__ partial, const float* __restrict__ misc,
                      float* __restrict__ out){
  __shared__ float red[16];
  int tid = threadIdx.x;
  float s = 0.f;
  for (int i = tid; i < NSNAP; i += 1024) s += partial[i];
  s = waveRed(s);
  if ((tid & 63) == 0) red[tid >> 6] = s;
  __syncthreads();
  if (tid == 0){
    float tot = 0.f;
    #pragma unroll
    for (int w = 0; w < 16; ++w) tot += red[w];
    out[0] = misc[0] - tot;
  }
}

// ---------------- host ----------------
extern "C" void kernel_launch(void* const* d_in, const int* in_sizes, int n_in,
                              void* d_out, int out_size, void* d_ws, size_t ws_size,
                              hipStream_t stream) {
  const float* times = (const float*)d_in[0];
  const int*   dims  = (const int*)d_in[1];
  const float* emb   = (const float*)d_in[2];
  const float* Wg    = (const float*)d_in[3];
  const float* bg    = (const float*)d_in[4];
  const float* Wint  = (const float*)d_in[5];
  const float* bint  = (const float*)d_in[6];
  const float* uin   = (const float*)d_in[7];
  const int*   tend  = (const int*)d_in[8];
  float* out = (float*)d_out;

  char* ws = (char*)d_ws;
  const size_t GX_OFF   = 0;                       // 129*6144*4 = 3,170,304
  const size_t WHB_OFF  = 3170304;                 // 12,582,912
  const size_t SC_OFF   = 15753216;                // 8,390,656 each (fp16)
  const size_t SCB_OFF  = 24143872;
  const size_t SD_OFF   = 32534528;
  const size_t SO_OFF   = 40925184;
  const size_t HBUF_OFF = 49315840;                // 2048 * 8B = 16,384 (tagged h words)
  const size_t MISC_OFF = 49332224;                // 256
  const size_t PART_OFF = 49332480;                // 16,388

  float*              Gx    = (float*)(ws + GX_OFF);
  unsigned int*       Whb   = (unsigned int*)(ws + WHB_OFF);
  __half*             Sc    = (__half*)(ws + SC_OFF);
  __half*             Scb   = (__half*)(ws + SCB_OFF);
  __half*             Sd    = (__half*)(ws + SD_OFF);
  __half*             So    = (__half*)(ws + SO_OFF);
  unsigned long long* hbuf  = (unsigned long long*)(ws + HBUF_OFF);
  float*              misc  = (float*)(ws + MISC_OFF);
  float*              part  = (float*)(ws + PART_OFF);

  const int SCAN_LDS = 98304 + 4096 + 4 * (NROWS + NROWS + 16);      // 102,848
  const int MC_LDS   = 64 * APITCH * 4 + 4 * H_ * 4 + 16 * 64 * 4;   // 151,808

  // host-side attribute set: not a stream op, safe under graph capture
  hipFuncSetAttribute((const void*)k_scan, hipFuncAttributeMaxDynamicSharedMemorySize, SCAN_LDS);
  hipFuncSetAttribute((const void*)k_mc,   hipFuncAttributeMaxDynamicSharedMemorySize, MC_LDS);

  k_gx<<<1536, 256, 0, stream>>>(Wg, bg, emb, Gx);
  k_pack<<<(NB_ * NROWS * 512 + 255) / 256, 256, 0, stream>>>(Wg, Whb);

  // Plain launch; co-residency by capacity: 128 blocks, 1 block/CU (102.8 KB LDS), 256 CUs.
  // Tag-embedded atomic handshake needs no zero-init (tags 1..4096 never match 0x00/0xAA poison).
  k_scan<<<dim3(NB_), dim3(1024), SCAN_LDS, stream>>>(times, dims, Gx, Whb, Wint, bint,
                                                      Sc, Scb, Sd, So, hbuf, misc);

  k_mc<<<NSNAP, 1024, MC_LDS, stream>>>(times, uin, Wint, bint, Sc, Scb, Sd, So, tend, part);
  k_red<<<1, 1024, 0, stream>>>(part, misc, out);
}